// Round 10
// baseline (99.864 us; speedup 1.0000x reference)
//
#include <hip/hip_runtime.h>

#define NB 16
#define SS 2048
#define DD 64

typedef __attribute__((ext_vector_type(8))) short short8;
typedef __attribute__((ext_vector_type(4))) float f32x4;

// SCALE * log2(e), folded so softmax exp is one v_mul + one v_exp
#define SCL2E 0.18033688011112042f

// async global->LDS, 16B per lane (LDS dest = wave-uniform base + lane*16)
#define GLOAD_LDS(g, l) __builtin_amdgcn_global_load_lds( \
    (const __attribute__((address_space(1))) void*)(g),   \
    (__attribute__((address_space(3))) void*)(l), 16, 0, 0)

// round-to-nearest-even f32 -> bf16 (as raw short)
__device__ __forceinline__ short f2bf(float f) {
  union { float f; unsigned u; } v; v.f = f;
  unsigned r = (v.u + 0x7fffu + ((v.u >> 16) & 1u)) >> 16;
  return (short)r;
}

// packed RNE f32x2 -> bf16x2 (no builtin on gfx950; guide T12)
__device__ __forceinline__ unsigned cvtpk_bf16(float lo, float hi) {
  unsigned r;
  asm("v_cvt_pk_bf16_f32 %0, %1, %2" : "=v"(r) : "v"(lo), "v"(hi));
  return r;
}

__device__ __forceinline__ short8 load_a_frag_f32(const float* p) {
  float4 u = *(const float4*)p;
  float4 w = *(const float4*)(p + 4);
  short8 r;
  r[0] = f2bf(u.x); r[1] = f2bf(u.y); r[2] = f2bf(u.z); r[3] = f2bf(u.w);
  r[4] = f2bf(w.x); r[5] = f2bf(w.y); r[6] = f2bf(w.z); r[7] = f2bf(w.w);
  return r;
}

// ---------------------------------------------------------------------------
// QKV projection (byte-identical to r9, harness-verified): pre-swizzled K
// stores and PV-permuted + swizzled V tiles.
// ---------------------------------------------------------------------------
__global__ __launch_bounds__(768) void proj_kernel(
    const float* __restrict__ x,
    const float* __restrict__ Wq, const float* __restrict__ bq,
    const float* __restrict__ Wk, const float* __restrict__ bk,
    const float* __restrict__ Wv, const float* __restrict__ bv,
    ushort* __restrict__ qo, ushort* __restrict__ ko, ushort* __restrict__ vt)
{
  __shared__ __align__(16) ushort Wt[3][64][72];   // W^T[n][k], bf16
  __shared__ __align__(16) ushort Vs[64][68];
  const int t = threadIdx.x;
#pragma unroll
  for (int i = 0; i < 4; ++i) {
    int idx = i * 3072 + t * 4;
    int m = idx >> 12, rem = idx & 4095;
    int kk = rem >> 6, n0 = rem & 63;
    const float* src = (m == 0 ? Wq : (m == 1 ? Wk : Wv));
    float4 w4 = *(const float4*)(src + rem);
    Wt[m][n0 + 0][kk] = (ushort)f2bf(w4.x);
    Wt[m][n0 + 1][kk] = (ushort)f2bf(w4.y);
    Wt[m][n0 + 2][kk] = (ushort)f2bf(w4.z);
    Wt[m][n0 + 3][kk] = (ushort)f2bf(w4.w);
  }
  __syncthreads();

  const int lane = t & 63, w = t >> 6;   // w in 0..11
  const int l15 = lane & 15, quad = lane >> 4;
  const int mm = w >> 2, rr = w & 3;     // matrix, row-quarter
  const int g = blockIdx.x * 64 + rr * 16 + l15;

  short8 b0 = load_a_frag_f32(x + (size_t)g * 64 + quad * 8);
  short8 b1 = load_a_frag_f32(x + (size_t)g * 64 + 32 + quad * 8);

  const float* bp = (mm == 0 ? bq : (mm == 1 ? bk : bv));
  ushort* outp = (mm == 0 ? qo : ko);

#pragma unroll
  for (int nt = 0; nt < 4; ++nt) {
    const ushort* ap = &Wt[mm][nt * 16 + l15][quad * 8];
    short8 a0 = *(const short8*)ap;
    short8 a1 = *(const short8*)(ap + 32);
    f32x4 acc = {0.f, 0.f, 0.f, 0.f};
    acc = __builtin_amdgcn_mfma_f32_16x16x32_bf16(a0, b0, acc, 0, 0, 0);
    acc = __builtin_amdgcn_mfma_f32_16x16x32_bf16(a1, b1, acc, 0, 0, 0);
    float4 bb = *(const float4*)(bp + nt * 16 + quad * 4);
    uint2 pk;
    pk.x = cvtpk_bf16(acc[0] + bb.x, acc[1] + bb.y);
    pk.y = cvtpk_bf16(acc[2] + bb.z, acc[3] + bb.w);
    if (mm == 2) {
      *(uint2*)&Vs[rr * 16 + l15][nt * 16 + quad * 4] = pk;
    } else {
      int colb = (nt * 16 + quad * 4) * 2;          // 8B-aligned byte col
      if (mm == 1) colb ^= (g & 7) << 4;            // K: swizzle within row
      *(uint2*)((char*)outp + (size_t)g * 128 + colb) = pk;
    }
  }
  __syncthreads();
  if (t < 256) {
    const int batch = blockIdx.x >> 5;
    const int ktile = blockIdx.x & 31;
    const int d = t >> 2, j0 = (t & 3) * 16;
    ushort tmp[16];
#pragma unroll
    for (int j = 0; j < 16; ++j) tmp[j] = Vs[j0 + j][d];
    // vtile[b][ktile][d][64 keys], row-swizzled AND column-permuted:
    // key s (within 32-key half) -> column quad(s)*8 + ct(s)*4 + r(s).
    char* base = (char*)vt + ((size_t)batch * SS * DD + ktile * 4096) * 2 + d * 128;
    const int sw = (d & 7) << 4;
    const int bcol = ((j0 >> 5) << 6) + (((j0 >> 4) & 1) << 3);
#pragma unroll
    for (int jj = 0; jj < 4; ++jj)
      *(uint2*)(base + ((bcol + jj * 16) ^ sw)) = ((uint2*)tmp)[jj];
  }
}

// ---------------------------------------------------------------------------
// exp + shuffle-free in-lane P repack + PV (harness-verified r9).
// ---------------------------------------------------------------------------
template<bool MASKED>
__device__ __forceinline__ void attn32(
    const f32x4 (&c)[2], float& l_acc, f32x4 (&acc)[4],
    const short8 (&vf)[4], int keybase, int qabs, int quad)
{
  unsigned pk[4];
#pragma unroll
  for (int ct = 0; ct < 2; ++ct) {
    float pe[4];
#pragma unroll
    for (int r = 0; r < 4; ++r) {
      float p = __builtin_amdgcn_exp2f(c[ct][r] * SCL2E);
      if (MASKED && (keybase + ct * 16 + quad * 4 + r > qabs)) p = 0.f;
      pe[r] = p;
      l_acc += p;
    }
    pk[ct * 2 + 0] = cvtpk_bf16(pe[0], pe[1]);
    pk[ct * 2 + 1] = cvtpk_bf16(pe[2], pe[3]);
  }
  int4 w4;
  w4.x = (int)pk[0]; w4.y = (int)pk[1]; w4.z = (int)pk[2]; w4.w = (int)pk[3];
  short8 pa = *(short8*)&w4;
  __builtin_amdgcn_s_setprio(1);
#pragma unroll
  for (int nt = 0; nt < 4; ++nt)
    acc[nt] = __builtin_amdgcn_mfma_f32_16x16x32_bf16(pa, vf[nt], acc[nt], 0, 0, 0);
  __builtin_amdgcn_s_setprio(0);
}

// cooperative stage of one 16KB K+V tile across 4 waves: wave seg stages 4KB
// (4 x gload_lds of 1KB each). K at lds[0..8191], V at lds[8192..16383].
__device__ __forceinline__ void stage_tile(
    char* lds, const ushort* kg, const ushort* vt,
    size_t bbyte, int kt, int seg, int lane)
{
  const char* src = (seg < 2)
      ? (const char*)kg + bbyte + (size_t)kt * 8192 + seg * 4096
      : (const char*)vt + bbyte + (size_t)kt * 8192 + (seg - 2) * 4096;
  char* dst = lds + seg * 4096;
#pragma unroll
  for (int i = 0; i < 4; ++i)
    GLOAD_LDS(src + i * 1024 + lane * 16, dst + i * 1024);
}

// ---------------------------------------------------------------------------
// Flash causal attention v11: 32 queries/block, FOUR waves (2 q-subtiles x
// 2 key-halves), grid 1024 -> 4 blocks/CU co-resident (vs 2 for the 512-thr
// version at VGPR~116). When one block sits in its stage-drain barrier,
// THREE other blocks compute (was one). Inner math identical to r9
// (shuffle-free P handoff, swizzled K/V, 2-buffer LDS staging).
// ---------------------------------------------------------------------------
__global__ __launch_bounds__(256) void attn_kernel(
    const ushort* __restrict__ qg, const ushort* __restrict__ kg,
    const ushort* __restrict__ vt, float* __restrict__ out)
{
  __shared__ __align__(16) char KV[2][16384];   // per buf: K 8KB | V 8KB

  const int t = threadIdx.x, bid = blockIdx.x;
  const int batch = (bid & 7) * 2 + ((bid >> 3) & 1);  // 2 batches per XCD
  const int qt = 63 - (bid >> 4);                      // 32q tile, heavy first
  const int q0 = qt * 32;
  const int lane = t & 63, w = t >> 6;                 // 4 waves
  const int l15 = lane & 15, quad = lane >> 4;
  const int h = w >> 1;                                // key half (0/1)
  const int qgi = w & 1;                               // query subtile
  const int qrow0 = q0 + qgi * 16;
  const size_t bbase = (size_t)batch * SS * DD;        // elements
  const size_t bbyte = bbase * 2;                      // bytes

  // Q fragments (B operand of swapped QK): lane l15 = query row
  const ushort* qp = qg + bbase + (size_t)(qrow0 + l15) * 64 + quad * 8;
  short8 a0 = *(const short8*)qp;
  short8 a1 = *(const short8*)(qp + 32);

  f32x4 acc[4];
  float l = 0.f;
#pragma unroll
  for (int nt = 0; nt < 4; ++nt) acc[nt] = (f32x4){0.f, 0.f, 0.f, 0.f};

  const int ktotal = ((q0 + 31) >> 6) + 1;   // 64-key tiles
  const int qabs = qrow0 + l15;

  stage_tile(&KV[0][0], kg, vt, bbyte, 0, w, lane);
  __syncthreads();   // drains vmcnt(0): buf0 ready

  int cur = 0;
  for (int kt = 0; kt < ktotal; ++kt) {
    if (kt + 1 < ktotal)
      stage_tile(&KV[cur ^ 1][0], kg, vt, bbyte, kt + 1, w, lane);

    const char* Kb = &KV[cur][0];
    const char* Vb = &KV[cur][8192];
    short8 kf0[2], kf1[2], vf[4];
#pragma unroll
    for (int c2 = 0; c2 < 2; ++c2) {
      int row = (2 * h + c2) * 16 + l15;      // key row in tile
      int sw = (row & 7) << 4;
      kf0[c2] = *(const short8*)(Kb + row * 128 + ((quad * 16) ^ sw));
      kf1[c2] = *(const short8*)(Kb + row * 128 + ((64 + quad * 16) ^ sw));
    }
#pragma unroll
    for (int nt = 0; nt < 4; ++nt) {
      int drow = nt * 16 + l15;               // d row in V tile
      int sv = (drow & 7) << 4;
      vf[nt] = *(const short8*)(Vb + drow * 128 + ((h * 64 + quad * 16) ^ sv));
    }

    // Swapped QK: c = mfma(K, Q) -> S^T; lane l15 = query.
    f32x4 c[2];
    __builtin_amdgcn_s_setprio(1);
#pragma unroll
    for (int c2 = 0; c2 < 2; ++c2) {
      f32x4 z = {0.f, 0.f, 0.f, 0.f};
      c[c2] = __builtin_amdgcn_mfma_f32_16x16x32_bf16(kf0[c2], a0, z, 0, 0, 0);
      c[c2] = __builtin_amdgcn_mfma_f32_16x16x32_bf16(kf1[c2], a1, c[c2], 0, 0, 0);
    }
    __builtin_amdgcn_s_setprio(0);

    const int keybase = kt * 64 + h * 32;
    if (kt == ktotal - 1)
      attn32<true >(c, l, acc, vf, keybase, qabs, quad);
    else
      attn32<false>(c, l, acc, vf, keybase, qabs, quad);

    __syncthreads();   // vmcnt(0) drain of stage + barrier
    cur ^= 1;
  }

  // l per-lane (q = l15); fold the 4 quads (each held different keys)
  l += __shfl_xor(l, 16);
  l += __shfl_xor(l, 32);

  __syncthreads();   // all waves done with staging buffers before reuse

  // 2-way combine of key-halves through the (now free) staging LDS
  float* S = (float*)&KV[0][qgi * 8192];
  if (h == 1) {
#pragma unroll
    for (int r = 0; r < 4; ++r)
#pragma unroll
      for (int nt = 0; nt < 4; ++nt)
        S[(quad * 4 + r) * 68 + nt * 16 + l15] = acc[nt][r];
    if (lane < 16) S[1088 + lane] = l;
  }
  __syncthreads();
  if (h == 0) {
    float lt = l + S[1088 + l15];   // total denom for q = l15
#pragma unroll
    for (int r = 0; r < 4; ++r) {
      float iv = 1.0f / __shfl(lt, quad * 4 + r);
      float* orow = out + bbase + (size_t)(qrow0 + quad * 4 + r) * 64 + l15;
#pragma unroll
      for (int nt = 0; nt < 4; ++nt)
        orow[nt * 16] = (acc[nt][r] + S[(quad * 4 + r) * 68 + nt * 16 + l15]) * iv;
    }
  }
}

extern "C" void kernel_launch(void* const* d_in, const int* in_sizes, int n_in,
                              void* d_out, int out_size, void* d_ws, size_t ws_size,
                              hipStream_t stream) {
  (void)in_sizes; (void)n_in; (void)out_size; (void)ws_size;
  const float* x  = (const float*)d_in[0];
  const float* Wq = (const float*)d_in[1];
  const float* bq = (const float*)d_in[2];
  const float* Wk = (const float*)d_in[3];
  const float* bk = (const float*)d_in[4];
  const float* Wv = (const float*)d_in[5];
  const float* bv = (const float*)d_in[6];
  float* out = (float*)d_out;

  ushort* qws = (ushort*)d_ws;                       // bf16 q: 4 MB
  ushort* kws = qws + (size_t)NB * SS * DD;          // bf16 k (swizzled): 4 MB
  ushort* vws = kws + (size_t)NB * SS * DD;          // bf16 vtile (swz+perm): 4 MB

  proj_kernel<<<dim3(NB * SS / 64), dim3(768), 0, stream>>>(
      x, Wq, bq, Wk, bk, Wv, bv, qws, kws, vws);
  attn_kernel<<<dim3(NB * (SS / 32)), dim3(256), 0, stream>>>(
      qws, kws, vws, out);
}